// Round 5
// baseline (261.004 us; speedup 1.0000x reference)
//
#include <hip/hip_runtime.h>

#define H 1024
#define E 64
#define BT 64          // tokens per block tile
#define BK 64          // k-columns staged per outer iteration
#define LDW (BK + 4)   // row stride 68 floats = 17 float4 (16B-aligned)

// 8x8-thread-tile MoE gate with in-block split-K x8 over a SHARED staging tile.
// Block = 512 thr = 8 waves; wave kg = tid>>6 owns k-slice [kg*8, kg*8+8) of
// each staged BK=64 panel; lane: tx = lane&7 (8 experts), ty = lane>>3 (8 toks).
// Why: R2/R4 measured an LDS-return-BW floor (16384 ds_read_b128/CU x ~12cyc
// = 82 us) from the 4x4 tile's 2 B/FMA. 8x8 tile halves that to 1 B/FMA
// (~98K cyc LDS vs 65K cyc VALU floor). Grid 512 = 2 blocks/CU exactly.
// Swizzle: f4-col phys = kkf ^ (row>>3); with stride 17 f4, a-read bank-quad
// = (r + kkf^ty) mod 8 and b-read = (c + kkf^tx) mod 8 -> both conflict-free.
__global__ __launch_bounds__(512, 4) void moe_gate_kernel(
    const float* __restrict__ x, const float* __restrict__ W,
    float* __restrict__ out, int T) {
  __shared__ float xs[BT][LDW];
  __shared__ float ws[E][LDW];
  __shared__ float ls[BT][E + 1];  // logits; stride 65 -> scan reads 2-way(free)

  const int tid  = threadIdx.x;
  const int kg   = tid >> 6;   // wave index = k-group (wave-uniform)
  const int lane = tid & 63;
  const int tx   = lane & 7;   // expert group: experts [8tx, 8tx+8)
  const int ty   = lane >> 3;  // token group:  tokens  [8ty, 8ty+8)
  const int t0   = blockIdx.x * BT;

  float acc[8][8];
#pragma unroll
  for (int r = 0; r < 8; ++r)
#pragma unroll
    for (int c = 0; c < 8; ++c) acc[r][c] = 0.f;

#pragma unroll 1
  for (int it = 0; it < H / BK; ++it) {
    // Cooperative stage: 1024 f4 slots per array, 2 per thread, coalesced
    // (16 consecutive lanes cover one 256 B row segment).
#pragma unroll
    for (int l = 0; l < 2; ++l) {
      int id  = tid + l * 512;
      int row = id >> 4;                 // 0..63
      int c4  = id & 15;                 // logical f4 column
      int pc4 = c4 ^ (row >> 3);         // XOR swizzle
      *(float4*)&xs[row][pc4 << 2] =
          *(const float4*)&x[(size_t)(t0 + row) * H + it * BK + (c4 << 2)];
      *(float4*)&ws[row][pc4 << 2] =
          *(const float4*)&W[(size_t)row * H + it * BK + (c4 << 2)];
    }
    __syncthreads();

    // This wave's two f4 k-steps of the panel: kkf = 2*kg + j.
#pragma unroll
    for (int j = 0; j < 2; ++j) {
      const int kkf = 2 * kg + j;
      float4 b[8];  // held: 8 experts x 4k = 32 VGPRs
#pragma unroll
      for (int c = 0; c < 8; ++c)
        b[c] = *(const float4*)&ws[tx * 8 + c][(kkf ^ tx) << 2];
#pragma unroll
      for (int r = 0; r < 8; ++r) {
        float4 a = *(const float4*)&xs[ty * 8 + r][(kkf ^ ty) << 2];  // streamed
#pragma unroll
        for (int c = 0; c < 8; ++c) {
          acc[r][c] += a.x * b[c].x;
          acc[r][c] += a.y * b[c].y;
          acc[r][c] += a.z * b[c].z;
          acc[r][c] += a.w * b[c].w;
        }
      }
    }
    __syncthreads();
  }

  // Cross-k-group reduction: sequential 8 passes (one wave each) into ls.
#pragma unroll 1
  for (int p = 0; p < 8; ++p) {
    if (kg == p) {
#pragma unroll
      for (int r = 0; r < 8; ++r)
#pragma unroll
        for (int c = 0; c < 8; ++c) {
          if (p == 0) ls[ty * 8 + r][tx * 8 + c] = acc[r][c];
          else        ls[ty * 8 + r][tx * 8 + c] += acc[r][c];
        }
    }
    __syncthreads();
  }

  // One lane per token: top-2 of logits == top-2 of softmax (monotonic);
  // tie-break lower index first (matches jax.lax.top_k). Epilogue identical
  // to R1/R2/R4 kernels that passed with absmax 0.
  if (tid < BT) {
    const int tk = tid;
    float m1 = -1e30f, m2 = -1e30f;
    int i1 = 0, i2 = 0;
#pragma unroll
    for (int e = 0; e < E; ++e) {
      float v = ls[tk][e];
      if (v > m1) {
        m2 = m1; i2 = i1;
        m1 = v;  i1 = e;
      } else if (v > m2) {
        m2 = v; i2 = e;
      }
    }
    float sden = 0.f;
#pragma unroll
    for (int e = 0; e < E; ++e) sden += expf(ls[tk][e] - m1);
    float p1 = 1.f / sden;            // exp(m1-m1)/sden
    float p2 = expf(m2 - m1) / sden;
    // second softmax over [p1, p2] (p1 >= p2 so exponent <= 0: stable)
    float e12 = expf(p2 - p1);
    float s1 = 1.f / (1.f + e12);
    float s2 = e12 * s1;

    size_t tt = (size_t)(t0 + tk);
    out[tt * 2 + 0] = s1;
    out[tt * 2 + 1] = s2;
    float* idxo = out + (size_t)2 * T;
    idxo[tt * 2 + 0] = (float)i1;
    idxo[tt * 2 + 1] = (float)i2;
  }

  // trailing scalar output: zeros(())
  if (blockIdx.x == 0 && tid == 0) out[(size_t)4 * T] = 0.f;
}

extern "C" void kernel_launch(void* const* d_in, const int* in_sizes, int n_in,
                              void* d_out, int out_size, void* d_ws, size_t ws_size,
                              hipStream_t stream) {
  const float* x = (const float*)d_in[0];
  const float* W = (const float*)d_in[1];
  float* out = (float*)d_out;
  const int T = in_sizes[0] / H;  // 32768 tokens
  dim3 grid(T / BT), block(512);
  hipLaunchKernelGGL(moe_gate_kernel, grid, block, 0, stream, x, W, out, T);
}

// Round 6
// 254.017 us; speedup vs baseline: 1.0275x; 1.0275x over previous
//
#include <hip/hip_runtime.h>

#define H 1024
#define E 64
#define BT 64          // tokens per block tile
#define BK 64          // k-columns staged per outer iteration
#define LDW (BK + 4)   // row stride 68 floats = 17 float4 (16B-aligned)

// Logits scratch layout (overlays xs): per-(token-block,expert-block) chunk of
// 68 floats -> f4 ops hit bank-quad (lane + 2r + j) mod 8 = conflict-free.
#define LSIDX(t, e) (((((t) >> 3) * 8 + ((e) >> 3)) * 68) + (((t) & 7) * 8) + ((e) & 7))

// 8x8-thread-tile MoE gate, in-block split-K x8 over a shared staging tile.
// R5 lessons baked in:
//  - __launch_bounds__(512,4) made the compiler cap VGPRs at 64 -> 15.9 MB
//    scratch spill (WRITE_SIZE counter). Use (512,2): cap >=128, demand ~115.
//  - ls[t][e] row-major reduction was 16-way bank-conflicted (6.07e6 counter);
//    per-thread-chunk layout above is conflict-free and float4-wide.
// Main loop unchanged from R5 (swizzle measured clean): 8192 ds_read_b128/CU
// ~= 98K cyc ~= 41 us LDS-pipe floor vs 65K cyc VALU floor.
__global__ __launch_bounds__(512, 2) void moe_gate_kernel(
    const float* __restrict__ x, const float* __restrict__ W,
    float* __restrict__ out, int T) {
  __shared__ float xs[BT][LDW];
  __shared__ float ws[E][LDW];
  float* lsf = (float*)xs;  // logits overlay: 64*68 floats = sizeof(xs) exactly

  const int tid  = threadIdx.x;
  const int kg   = tid >> 6;   // wave index = k-group (wave-uniform)
  const int lane = tid & 63;
  const int tx   = lane & 7;   // expert group: experts [8tx, 8tx+8)
  const int ty   = lane >> 3;  // token group:  tokens  [8ty, 8ty+8)
  const int t0   = blockIdx.x * BT;

  float acc[8][8];
#pragma unroll
  for (int r = 0; r < 8; ++r)
#pragma unroll
    for (int c = 0; c < 8; ++c) acc[r][c] = 0.f;

#pragma unroll 1
  for (int it = 0; it < H / BK; ++it) {
    // Cooperative stage: 1024 f4 slots per array, 2 per thread, coalesced.
#pragma unroll
    for (int l = 0; l < 2; ++l) {
      int id  = tid + l * 512;
      int row = id >> 4;                 // 0..63
      int c4  = id & 15;                 // logical f4 column
      int pc4 = c4 ^ (row >> 3);         // XOR swizzle
      *(float4*)&xs[row][pc4 << 2] =
          *(const float4*)&x[(size_t)(t0 + row) * H + it * BK + (c4 << 2)];
      *(float4*)&ws[row][pc4 << 2] =
          *(const float4*)&W[(size_t)row * H + it * BK + (c4 << 2)];
    }
    __syncthreads();

    // This wave's two f4 k-steps of the panel: kkf = 2*kg + j.
#pragma unroll
    for (int j = 0; j < 2; ++j) {
      const int kkf = 2 * kg + j;
      float4 b[8];  // held: 8 experts x 4k = 32 VGPRs
#pragma unroll
      for (int c = 0; c < 8; ++c)
        b[c] = *(const float4*)&ws[tx * 8 + c][(kkf ^ tx) << 2];
#pragma unroll
      for (int r = 0; r < 8; ++r) {
        float4 a = *(const float4*)&xs[ty * 8 + r][(kkf ^ ty) << 2];  // streamed
#pragma unroll
        for (int c = 0; c < 8; ++c) {
          acc[r][c] += a.x * b[c].x;
          acc[r][c] += a.y * b[c].y;
          acc[r][c] += a.z * b[c].z;
          acc[r][c] += a.w * b[c].w;
        }
      }
    }
    __syncthreads();
  }

  // Cross-k-group reduction: 8 sequential passes, float4, conflict-free.
  // All waves' lane L target the same 68-float chunk (base = lane*68).
  {
    float* chunk = lsf + lane * 68;
#pragma unroll 1
    for (int p = 0; p < 8; ++p) {
      if (kg == p) {
#pragma unroll
        for (int r = 0; r < 8; ++r) {
          float4 lo = make_float4(acc[r][0], acc[r][1], acc[r][2], acc[r][3]);
          float4 hi = make_float4(acc[r][4], acc[r][5], acc[r][6], acc[r][7]);
          if (p == 0) {
            *(float4*)&chunk[r * 8 + 0] = lo;
            *(float4*)&chunk[r * 8 + 4] = hi;
          } else {
            float4 olo = *(const float4*)&chunk[r * 8 + 0];
            float4 ohi = *(const float4*)&chunk[r * 8 + 4];
            olo.x += lo.x; olo.y += lo.y; olo.z += lo.z; olo.w += lo.w;
            ohi.x += hi.x; ohi.y += hi.y; ohi.z += hi.z; ohi.w += hi.w;
            *(float4*)&chunk[r * 8 + 0] = olo;
            *(float4*)&chunk[r * 8 + 4] = ohi;
          }
        }
      }
      __syncthreads();
    }
  }

  // One lane per token: top-2 of logits == top-2 of softmax (monotonic);
  // tie-break lower index first (matches jax.lax.top_k). Same math as the
  // absmax-0 kernels R1/R2/R4/R5.
  if (tid < BT) {
    const int tk = tid;
    float m1 = -1e30f, m2 = -1e30f;
    int i1 = 0, i2 = 0;
#pragma unroll
    for (int e = 0; e < E; ++e) {
      float v = lsf[LSIDX(tk, e)];
      if (v > m1) {
        m2 = m1; i2 = i1;
        m1 = v;  i1 = e;
      } else if (v > m2) {
        m2 = v; i2 = e;
      }
    }
    float sden = 0.f;
#pragma unroll
    for (int e = 0; e < E; ++e) sden += expf(lsf[LSIDX(tk, e)] - m1);
    float p1 = 1.f / sden;            // exp(m1-m1)/sden
    float p2 = expf(m2 - m1) / sden;
    // second softmax over [p1, p2] (p1 >= p2 so exponent <= 0: stable)
    float e12 = expf(p2 - p1);
    float s1 = 1.f / (1.f + e12);
    float s2 = e12 * s1;

    size_t tt = (size_t)(t0 + tk);
    out[tt * 2 + 0] = s1;
    out[tt * 2 + 1] = s2;
    float* idxo = out + (size_t)2 * T;
    idxo[tt * 2 + 0] = (float)i1;
    idxo[tt * 2 + 1] = (float)i2;
  }

  // trailing scalar output: zeros(())
  if (blockIdx.x == 0 && tid == 0) out[(size_t)4 * T] = 0.f;
}

extern "C" void kernel_launch(void* const* d_in, const int* in_sizes, int n_in,
                              void* d_out, int out_size, void* d_ws, size_t ws_size,
                              hipStream_t stream) {
  const float* x = (const float*)d_in[0];
  const float* W = (const float*)d_in[1];
  float* out = (float*)d_out;
  const int T = in_sizes[0] / H;  // 32768 tokens
  dim3 grid(T / BT), block(512);
  hipLaunchKernelGGL(moe_gate_kernel, grid, block, 0, stream, x, W, out, T);
}

// Round 7
// 246.057 us; speedup vs baseline: 1.0607x; 1.0324x over previous
//
#include <hip/hip_runtime.h>

#define H 1024
#define E 64
#define BT 64          // tokens per block tile
#define BK 64          // k-columns staged per outer iteration
#define LDW (BK + 4)   // row stride 68 floats = 17 float4 (16B-aligned)
#define NIT (H / BK)   // 16

// Logits scratch layout (overlays xs[0]): per-lane chunk of 68 floats ->
// f4 ops hit bank-quad (lane + 2r + j) mod 8 = conflict-free.
#define LSIDX(t, e) (((((t) >> 3) * 8 + ((e) >> 3)) * 68) + (((t) & 7) * 8) + ((e) & 7))

// 8x8-thread-tile MoE gate, split-K x8, DOUBLE-BUFFERED LDS + register
// prefetch. R6 diagnosis: spill & conflicts fixed, but 121 us with VALU 30% /
// LDS 34% busy = per-iteration HBM-load latency serialized behind 2 barriers
// at 2 blocks/CU. Fix: (1) two LDS buffers -> ONE barrier/iter; (2) issue
// tile i+1's global loads BEFORE compute of tile i -> ~10K cyc of compute
// covers the ~900 cyc HBM latency; vmcnt wait lands at the ds_write, off the
// critical path. Inner loop unchanged (swizzle measured conflict-free).
// Floor: LDS pipe 8192 ds_read_b128/CU x 12 cyc = 41 us.
__global__ __launch_bounds__(512, 2) void moe_gate_kernel(
    const float* __restrict__ x, const float* __restrict__ W,
    float* __restrict__ out, int T) {
  __shared__ float xs[2][BT][LDW];
  __shared__ float ws[2][E][LDW];
  float* lsf = (float*)xs;  // logits overlay on xs[0] (64*68 floats exactly)

  const int tid  = threadIdx.x;
  const int kg   = tid >> 6;   // wave index = k-group (wave-uniform)
  const int lane = tid & 63;
  const int tx   = lane & 7;   // expert group: experts [8tx, 8tx+8)
  const int ty   = lane >> 3;  // token group:  tokens  [8ty, 8ty+8)
  const int t0   = blockIdx.x * BT;

  // Staging slot assignment (2 f4 slots per thread per array).
  const int id0 = tid, id1 = tid + 512;
  const int row0 = id0 >> 4, c40 = id0 & 15, pc40 = c40 ^ (row0 >> 3);
  const int row1 = id1 >> 4, c41 = id1 & 15, pc41 = c41 ^ (row1 >> 3);
  const float* xg0 = &x[(size_t)(t0 + row0) * H + (c40 << 2)];
  const float* xg1 = &x[(size_t)(t0 + row1) * H + (c41 << 2)];
  const float* wg0 = &W[(size_t)row0 * H + (c40 << 2)];
  const float* wg1 = &W[(size_t)row1 * H + (c41 << 2)];

  float acc[8][8];
#pragma unroll
  for (int r = 0; r < 8; ++r)
#pragma unroll
    for (int c = 0; c < 8; ++c) acc[r][c] = 0.f;

  // Prologue: tile 0 -> buf 0.
  {
    float4 nx0 = *(const float4*)xg0;
    float4 nx1 = *(const float4*)xg1;
    float4 nw0 = *(const float4*)wg0;
    float4 nw1 = *(const float4*)wg1;
    *(float4*)&xs[0][row0][pc40 << 2] = nx0;
    *(float4*)&xs[0][row1][pc41 << 2] = nx1;
    *(float4*)&ws[0][row0][pc40 << 2] = nw0;
    *(float4*)&ws[0][row1][pc41 << 2] = nw1;
  }
  __syncthreads();

#pragma unroll 1
  for (int it = 0; it < NIT; ++it) {
    const int cur = it & 1;

    // Prefetch tile it+1 (in flight across the whole compute phase).
    float4 nx0, nx1, nw0, nw1;
    if (it < NIT - 1) {
      const int ko = (it + 1) * BK;
      nx0 = *(const float4*)(xg0 + ko);
      nx1 = *(const float4*)(xg1 + ko);
      nw0 = *(const float4*)(wg0 + ko);
      nw1 = *(const float4*)(wg1 + ko);
    }

    // Compute on buf[cur]: this wave's two f4 k-steps, kkf = 2*kg + j.
    const float(*xsh)[LDW] = xs[cur];
    const float(*wsh)[LDW] = ws[cur];
#pragma unroll
    for (int j = 0; j < 2; ++j) {
      const int kkf = 2 * kg + j;
      float4 b[8];  // held: 8 experts x 4k = 32 VGPRs
#pragma unroll
      for (int c = 0; c < 8; ++c)
        b[c] = *(const float4*)&wsh[tx * 8 + c][(kkf ^ tx) << 2];
#pragma unroll
      for (int r = 0; r < 8; ++r) {
        float4 a = *(const float4*)&xsh[ty * 8 + r][(kkf ^ ty) << 2];
#pragma unroll
        for (int c = 0; c < 8; ++c) {
          acc[r][c] += a.x * b[c].x;
          acc[r][c] += a.y * b[c].y;
          acc[r][c] += a.z * b[c].z;
          acc[r][c] += a.w * b[c].w;
        }
      }
    }

    // Stage tile it+1 into buf[cur^1]; single barrier per iteration.
    // (Safe: reads of buf[cur^1] all happened before the PREVIOUS barrier.)
    if (it < NIT - 1) {
      const int nxt = cur ^ 1;
      *(float4*)&xs[nxt][row0][pc40 << 2] = nx0;
      *(float4*)&xs[nxt][row1][pc41 << 2] = nx1;
      *(float4*)&ws[nxt][row0][pc40 << 2] = nw0;
      *(float4*)&ws[nxt][row1][pc41 << 2] = nw1;
      __syncthreads();
    }
  }

  __syncthreads();  // all waves done with both buffers before lsf overlay

  // Cross-k-group reduction: 8 sequential passes, float4, conflict-free.
  {
    float* chunk = lsf + lane * 68;
#pragma unroll 1
    for (int p = 0; p < 8; ++p) {
      if (kg == p) {
#pragma unroll
        for (int r = 0; r < 8; ++r) {
          float4 lo = make_float4(acc[r][0], acc[r][1], acc[r][2], acc[r][3]);
          float4 hi = make_float4(acc[r][4], acc[r][5], acc[r][6], acc[r][7]);
          if (p == 0) {
            *(float4*)&chunk[r * 8 + 0] = lo;
            *(float4*)&chunk[r * 8 + 4] = hi;
          } else {
            float4 olo = *(const float4*)&chunk[r * 8 + 0];
            float4 ohi = *(const float4*)&chunk[r * 8 + 4];
            olo.x += lo.x; olo.y += lo.y; olo.z += lo.z; olo.w += lo.w;
            ohi.x += hi.x; ohi.y += hi.y; ohi.z += hi.z; ohi.w += hi.w;
            *(float4*)&chunk[r * 8 + 0] = olo;
            *(float4*)&chunk[r * 8 + 4] = ohi;
          }
        }
      }
      __syncthreads();
    }
  }

  // One lane per token: top-2 of logits == top-2 of softmax (monotonic);
  // tie-break lower index first (matches jax.lax.top_k). Same math as the
  // absmax-0 kernels R1/R2/R4/R5/R6.
  if (tid < BT) {
    const int tk = tid;
    float m1 = -1e30f, m2 = -1e30f;
    int i1 = 0, i2 = 0;
#pragma unroll
    for (int e = 0; e < E; ++e) {
      float v = lsf[LSIDX(tk, e)];
      if (v > m1) {
        m2 = m1; i2 = i1;
        m1 = v;  i1 = e;
      } else if (v > m2) {
        m2 = v; i2 = e;
      }
    }
    float sden = 0.f;
#pragma unroll
    for (int e = 0; e < E; ++e) sden += expf(lsf[LSIDX(tk, e)] - m1);
    float p1 = 1.f / sden;            // exp(m1-m1)/sden
    float p2 = expf(m2 - m1) / sden;
    // second softmax over [p1, p2] (p1 >= p2 so exponent <= 0: stable)
    float e12 = expf(p2 - p1);
    float s1 = 1.f / (1.f + e12);
    float s2 = e12 * s1;

    size_t tt = (size_t)(t0 + tk);
    out[tt * 2 + 0] = s1;
    out[tt * 2 + 1] = s2;
    float* idxo = out + (size_t)2 * T;
    idxo[tt * 2 + 0] = (float)i1;
    idxo[tt * 2 + 1] = (float)i2;
  }

  // trailing scalar output: zeros(())
  if (blockIdx.x == 0 && tid == 0) out[(size_t)4 * T] = 0.f;
}

extern "C" void kernel_launch(void* const* d_in, const int* in_sizes, int n_in,
                              void* d_out, int out_size, void* d_ws, size_t ws_size,
                              hipStream_t stream) {
  const float* x = (const float*)d_in[0];
  const float* W = (const float*)d_in[1];
  float* out = (float*)d_out;
  const int T = in_sizes[0] / H;  // 32768 tokens
  dim3 grid(T / BT), block(512);
  hipLaunchKernelGGL(moe_gate_kernel, grid, block, 0, stream, x, W, out, T);
}